// Round 1
// baseline (1195.084 us; speedup 1.0000x reference)
//
#include <hip/hip_runtime.h>
#include <hip/hip_bf16.h>

// Mix2Layer: out[b,o] = sum_k relu(sum_i x[b,i]*w1[i,o,k] + b1[o,k]) * (sum_i x[b,i]*w2[i,o,k]) + b2[o]
// B=2048, DIN=2048, DOUT=2048, K=16.  Treat N' = o*16+k (w row-major [DIN][32768]).
// Fused dual-GEMM, bf16 MFMA 16x16x32, fp32 accum, epilogue k-reduce via shfl_xor.

typedef __bf16 bf16;
typedef bf16 bf16x8 __attribute__((ext_vector_type(8)));
typedef bf16 bf16x4 __attribute__((ext_vector_type(4)));
typedef float f32x4 __attribute__((ext_vector_type(4)));

#define DIN_   2048
#define DOUT_  2048
#define NP_    32768   // DOUT*K
#define BM_    128
#define BN_    128
#define BK_    64
#define NTHR_  512
#define KSTEPS_ 32     // DIN / BK
#define MT_    16      // 2048/128 m-tiles
// LDS per buffer: A 128x64 bf16 (16KB) + B1 128x64 (16KB) + B2 128x64 (16KB) = 48KB
#define BUFBYTES_ 49152

__device__ __forceinline__ bf16x8 cvt8(f32x4 a, f32x4 b) {
    bf16x8 v;
    v[0] = (bf16)a[0]; v[1] = (bf16)a[1]; v[2] = (bf16)a[2]; v[3] = (bf16)a[3];
    v[4] = (bf16)b[0]; v[5] = (bf16)b[1]; v[6] = (bf16)b[2]; v[7] = (bf16)b[3];
    return v;
}

__global__ __launch_bounds__(NTHR_)
void mix2_fused(const float* __restrict__ x, const float* __restrict__ w1,
                const float* __restrict__ b1, const float* __restrict__ w2,
                const float* __restrict__ b2, float* __restrict__ out)
{
    __shared__ alignas(16) char lds[2 * BUFBYTES_];

    const int tid  = threadIdx.x;
    const int lane = tid & 63;
    const int wid  = tid >> 6;     // 0..7
    const int wm   = wid >> 2;     // 0..1  (64-row slab)
    const int wn   = wid & 3;      // 0..3  (32-col slab)

    // XCD-aware swizzle (grid 4096, 4096%8==0 -> simple bijective form).
    // Consecutive logical bids share a W-panel (same nt); group them per XCD.
    const int nwg = gridDim.x;
    const int bid = (blockIdx.x & 7) * (nwg >> 3) + (blockIdx.x >> 3);
    const int mt  = bid & (MT_ - 1);
    const int nt  = bid >> 4;

    const int lk  = lane & 15;     // MFMA col / k-index within o
    const int lg  = lane >> 4;     // k-subgroup
    const int swz = (lane & 7) << 4;

    // ---- staging thread mapping ----
    // A: 128x64 fp32 tile; 1024 chunks of 8 floats; thread handles chunk tid (+512)
    const int a_row  = tid >> 3;            // 0..63 (and +64)
    const int a_col8 = tid & 7;             // 8-float column block
    // B: per matrix 64(i)x128(n') tile as 4x4 blocks; thread handles one block per matrix
    const int b_ib = ((tid >> 5) & 15) << 2;  // i offset 0..60
    const int b_nb = (tid & 31) << 2;         // n' offset 0..124

    const float* pa  = x  + (size_t)(mt * BM_ + a_row) * DIN_ + a_col8 * 8;
    const float* pb1 = w1 + (size_t)b_ib * NP_ + (size_t)nt * BN_ + b_nb;
    const float* pb2 = w2 + (size_t)b_ib * NP_ + (size_t)nt * BN_ + b_nb;

    const int aswz   = (a_col8 * 16) ^ ((a_row & 7) << 4);
    const int aoffw0 = a_row * 128 + aswz;
    const int aoffw1 = (a_row + 64) * 128 + aswz;   // (a_row+64)&7 == a_row&7

    // fragment read offsets (row part); k part XORed with swz per kb
    int aoff[4], boff1[2], boff2[2];
#pragma unroll
    for (int fm = 0; fm < 4; ++fm) aoff[fm] = (wm * 64 + fm * 16 + lk) * 128;
#pragma unroll
    for (int fn = 0; fn < 2; ++fn) {
        const int n = wn * 32 + fn * 16 + lk;
        boff1[fn] = 16384 + n * 128;
        boff2[fn] = 32768 + n * 128;
    }
    const int kp0 = (lg * 16) ^ swz;
    const int kp1 = (64 + lg * 16) ^ swz;

    f32x4 acc1[4][2], acc2[4][2];
#pragma unroll
    for (int i = 0; i < 4; ++i)
#pragma unroll
        for (int j = 0; j < 2; ++j) {
            acc1[i][j] = (f32x4){0.f, 0.f, 0.f, 0.f};
            acc2[i][j] = (f32x4){0.f, 0.f, 0.f, 0.f};
        }

    f32x4 rA[4], rB1[4], rB2[4];

    auto LOAD = [&](int kt) {
        const float* a0 = pa + kt * BK_;
        rA[0] = *(const f32x4*)(a0);
        rA[1] = *(const f32x4*)(a0 + 4);
        rA[2] = *(const f32x4*)(a0 + (size_t)64 * DIN_);
        rA[3] = *(const f32x4*)(a0 + (size_t)64 * DIN_ + 4);
        const float* q1 = pb1 + (size_t)kt * BK_ * NP_;
        const float* q2 = pb2 + (size_t)kt * BK_ * NP_;
#pragma unroll
        for (int j = 0; j < 4; ++j) {
            rB1[j] = *(const f32x4*)(q1 + (size_t)j * NP_);
            rB2[j] = *(const f32x4*)(q2 + (size_t)j * NP_);
        }
    };

    auto STORE = [&](char* s) {
        *(bf16x8*)(s + aoffw0) = cvt8(rA[0], rA[1]);
        *(bf16x8*)(s + aoffw1) = cvt8(rA[2], rA[3]);
        char* s1 = s + 16384;
        char* s2 = s + 32768;
#pragma unroll
        for (int c = 0; c < 4; ++c) {
            const int n   = b_nb + c;
            const int off = n * 128 + ((b_ib * 2) ^ ((n & 7) << 4));
            bf16x4 v1, v2;
            v1[0] = (bf16)rB1[0][c]; v1[1] = (bf16)rB1[1][c];
            v1[2] = (bf16)rB1[2][c]; v1[3] = (bf16)rB1[3][c];
            v2[0] = (bf16)rB2[0][c]; v2[1] = (bf16)rB2[1][c];
            v2[2] = (bf16)rB2[2][c]; v2[3] = (bf16)rB2[3][c];
            *(bf16x4*)(s1 + off) = v1;   // B_lds[n'][i] k-contiguous (transposed)
            *(bf16x4*)(s2 + off) = v2;
        }
    };

    auto COMPUTE = [&](const char* s) {
#pragma unroll
        for (int kb = 0; kb < 2; ++kb) {
            const int kp = kb ? kp1 : kp0;
            bf16x8 a[4], u[2], v[2];
#pragma unroll
            for (int fm = 0; fm < 4; ++fm) a[fm] = *(const bf16x8*)(s + aoff[fm] + kp);
#pragma unroll
            for (int fn = 0; fn < 2; ++fn) u[fn] = *(const bf16x8*)(s + boff1[fn] + kp);
#pragma unroll
            for (int fn = 0; fn < 2; ++fn) v[fn] = *(const bf16x8*)(s + boff2[fn] + kp);
#pragma unroll
            for (int fm = 0; fm < 4; ++fm)
#pragma unroll
                for (int fn = 0; fn < 2; ++fn) {
                    acc1[fm][fn] = __builtin_amdgcn_mfma_f32_16x16x32_bf16(a[fm], u[fn], acc1[fm][fn], 0, 0, 0);
                    acc2[fm][fn] = __builtin_amdgcn_mfma_f32_16x16x32_bf16(a[fm], v[fn], acc2[fm][fn], 0, 0, 0);
                }
        }
    };

    char* buf0 = lds;
    char* buf1 = lds + BUFBYTES_;

    LOAD(0);
    STORE(buf0);
    __syncthreads();

    for (int kt = 0; kt < KSTEPS_; ++kt) {
        if (kt + 1 < KSTEPS_) LOAD(kt + 1);          // issue early; lands during COMPUTE
        COMPUTE((kt & 1) ? buf1 : buf0);
        if (kt + 1 < KSTEPS_) {
            STORE((kt & 1) ? buf0 : buf1);           // other buffer; single barrier/iter
            __syncthreads();
        }
    }

    // ---- epilogue: out[b,o] = sum_{k=lane&15} relu(h1+b1) * h2 + b2 ----
    const int obase = nt * 8 + wn * 2;
#pragma unroll
    for (int fn = 0; fn < 2; ++fn) {
        const int o = obase + fn;
        const float bb1 = b1[(size_t)o * 16 + lk];
        const float bb2 = b2[o];
#pragma unroll
        for (int fm = 0; fm < 4; ++fm) {
#pragma unroll
            for (int j = 0; j < 4; ++j) {
                float g = fmaxf(acc1[fm][fn][j] + bb1, 0.f);
                float p = g * acc2[fm][fn][j];
                p += __shfl_xor(p, 1);
                p += __shfl_xor(p, 2);
                p += __shfl_xor(p, 4);
                p += __shfl_xor(p, 8);
                if (lk == 0) {
                    const int brow = mt * BM_ + wm * 64 + fm * 16 + lg * 4 + j;
                    out[(size_t)brow * DOUT_ + o] = p + bb2;
                }
            }
        }
    }
}

extern "C" void kernel_launch(void* const* d_in, const int* in_sizes, int n_in,
                              void* d_out, int out_size, void* d_ws, size_t ws_size,
                              hipStream_t stream) {
    (void)in_sizes; (void)n_in; (void)out_size; (void)d_ws; (void)ws_size;
    const float* x  = (const float*)d_in[0];
    const float* w1 = (const float*)d_in[1];
    const float* b1 = (const float*)d_in[2];
    const float* w2 = (const float*)d_in[3];
    const float* b2 = (const float*)d_in[4];
    float* out = (float*)d_out;

    dim3 grid(MT_ * (NP_ / BN_));   // 16 * 256 = 4096
    dim3 block(NTHR_);
    hipLaunchKernelGGL(mix2_fused, grid, block, 0, stream, x, w1, b1, w2, b2, out);
}

// Round 2
// 758.602 us; speedup vs baseline: 1.5754x; 1.5754x over previous
//
#include <hip/hip_runtime.h>
#include <hip/hip_bf16.h>

// Mix2Layer: out[b,o] = sum_k relu(sum_i x[b,i]*w1[i,o,k] + b1[o,k]) * (sum_i x[b,i]*w2[i,o,k]) + b2[o]
// B=2048, DIN=2048, DOUT=2048, K=16.  N' = o*16+k (w row-major [DIN][32768]).
//
// Fast path (needs ws >= 264MB):
//   1) xcvt:   x fp32 -> bf16               (8 MB)
//   2) wtrans: w[i][n'] fp32 -> wt[n'][i] bf16 (k-major, 128 MB each)
//   3) mix2_gemm: dual-B bf16 GEMM, global_load_lds staging (m97 structure),
//      BK=32, 128x128 tile, 48KB LDS dbuf (2-3 blocks/CU), swizzled reads.
// Fallback: round-1 in-kernel-transpose kernel (verified passing).

typedef __bf16 bf16;
typedef bf16 bf16x8 __attribute__((ext_vector_type(8)));
typedef bf16 bf16x4 __attribute__((ext_vector_type(4)));
typedef float f32x4 __attribute__((ext_vector_type(4)));

typedef __attribute__((address_space(1))) const void gco_void;
typedef __attribute__((address_space(3))) void lds_void;

#define DIN_   2048
#define DOUT_  2048
#define NP_    32768   // DOUT*K

__device__ __forceinline__ bf16x8 cvt8(f32x4 a, f32x4 b) {
    bf16x8 v;
    v[0] = (bf16)a[0]; v[1] = (bf16)a[1]; v[2] = (bf16)a[2]; v[3] = (bf16)a[3];
    v[4] = (bf16)b[0]; v[5] = (bf16)b[1]; v[6] = (bf16)b[2]; v[7] = (bf16)b[3];
    return v;
}

// ---------------- prep 1: x fp32 -> bf16 ----------------
__global__ __launch_bounds__(256)
void xcvt(const float* __restrict__ x, bf16* __restrict__ xb) {
    const size_t i = ((size_t)blockIdx.x * 256 + threadIdx.x) * 8;
    f32x4 a = *(const f32x4*)(x + i);
    f32x4 b = *(const f32x4*)(x + i + 4);
    *(bf16x8*)(xb + i) = cvt8(a, b);
}

// ---------------- prep 2: w[i][n'] fp32 -> wt[n'][i] bf16 ----------------
// 64x64 tile via padded fp32 LDS; all 4 access sides coalesced/conflict-free.
__global__ __launch_bounds__(256)
void wtrans(const float* __restrict__ w1, const float* __restrict__ w2,
            bf16* __restrict__ w1t, bf16* __restrict__ w2t) {
    __shared__ float s[64][65];
    const int t  = threadIdx.x;
    const int lr = t >> 4;      // 0..15
    const int lq = t & 15;      // 0..15
    const int n0 = blockIdx.x * 64;
    const int i0 = blockIdx.y * 64;
    const float* src = blockIdx.z ? w2 : w1;
    bf16*        dst = blockIdx.z ? w2t : w1t;
#pragma unroll
    for (int r = 0; r < 4; ++r) {
        const int il = lr + 16 * r;
        f32x4 v = *(const f32x4*)(src + (size_t)(i0 + il) * NP_ + n0 + lq * 4);
        s[il][lq * 4 + 0] = v[0]; s[il][lq * 4 + 1] = v[1];
        s[il][lq * 4 + 2] = v[2]; s[il][lq * 4 + 3] = v[3];
    }
    __syncthreads();
#pragma unroll
    for (int r = 0; r < 4; ++r) {
        const int nl = lr + 16 * r;
        bf16x4 o;
        o[0] = (bf16)s[lq * 4 + 0][nl]; o[1] = (bf16)s[lq * 4 + 1][nl];
        o[2] = (bf16)s[lq * 4 + 2][nl]; o[3] = (bf16)s[lq * 4 + 3][nl];
        *(bf16x4*)(dst + (size_t)(n0 + nl) * DIN_ + i0 + lq * 4) = o;
    }
}

// ---------------- main: dual-B bf16 GEMM + fused epilogue ----------------
// Tile 128(m) x 128(n'), BK=32, 8 waves (2x4), wave tile 64x32.
// LDS: 2 buffers x (A 8K + B1 8K + B2 8K) = 48KB.
// Staging: 3x global_load_lds(16B)/thread/K-step, linear LDS dest,
// pre-swizzled global source: phys slot (t&3) holds data slot (t&3)^((row>>1)&3).
// Read: kp = (lg ^ ((lk>>1)&3))*16  -> 2 lanes/bank-group (free).
__global__ __launch_bounds__(512, 4)
void mix2_gemm(const bf16* __restrict__ xb, const bf16* __restrict__ w1t,
               const bf16* __restrict__ w2t, const float* __restrict__ b1,
               const float* __restrict__ b2, float* __restrict__ out)
{
    __shared__ alignas(16) char lds[49152];

    const int tid  = threadIdx.x;
    const int lane = tid & 63;
    const int wid  = tid >> 6;
    const int wm   = wid >> 2;
    const int wn   = wid & 3;
    const int lk   = lane & 15;
    const int lg   = lane >> 4;

    const int nwg = gridDim.x;
    const int bid = (blockIdx.x & 7) * (nwg >> 3) + (blockIdx.x >> 3);
    const int mt  = bid & 15;
    const int nt  = bid >> 4;

    // staging: thread t -> (row = t>>2, phys slot = t&3), src slot pre-swizzled
    const int srow = tid >> 2;
    const int sp   = (tid & 3) ^ ((srow >> 1) & 3);
    const bf16* gA  = xb  + (size_t)(mt * 128 + srow) * DIN_ + sp * 8;
    const bf16* gB1 = w1t + (size_t)(nt * 128 + srow) * DIN_ + sp * 8;
    const bf16* gB2 = w2t + (size_t)(nt * 128 + srow) * DIN_ + sp * 8;

    const int kp = (lg ^ ((lk >> 1) & 3)) * 16;
    int aoff[4], boff[2];
#pragma unroll
    for (int fm = 0; fm < 4; ++fm) aoff[fm] = (wm * 64 + fm * 16 + lk) * 64 + kp;
#pragma unroll
    for (int fn = 0; fn < 2; ++fn) boff[fn] = (wn * 32 + fn * 16 + lk) * 64 + kp;

    f32x4 acc1[4][2], acc2[4][2];
#pragma unroll
    for (int i = 0; i < 4; ++i)
#pragma unroll
        for (int j = 0; j < 2; ++j) {
            acc1[i][j] = (f32x4){0.f, 0.f, 0.f, 0.f};
            acc2[i][j] = (f32x4){0.f, 0.f, 0.f, 0.f};
        }

    auto STAGE = [&](int buf, int kt) {
        char* base = lds + buf * 24576;
        const int c = kt * 32;
        __builtin_amdgcn_global_load_lds((gco_void*)(gA  + c), (lds_void*)(base +         wid * 1024), 16, 0, 0);
        __builtin_amdgcn_global_load_lds((gco_void*)(gB1 + c), (lds_void*)(base +  8192 + wid * 1024), 16, 0, 0);
        __builtin_amdgcn_global_load_lds((gco_void*)(gB2 + c), (lds_void*)(base + 16384 + wid * 1024), 16, 0, 0);
    };

    auto COMPUTE = [&](int buf) {
        const char* sA  = lds + buf * 24576;
        const char* sB1 = sA + 8192;
        const char* sB2 = sA + 16384;
        bf16x8 a[4], u[2], v[2];
#pragma unroll
        for (int fm = 0; fm < 4; ++fm) a[fm] = *(const bf16x8*)(sA + aoff[fm]);
#pragma unroll
        for (int fn = 0; fn < 2; ++fn) u[fn] = *(const bf16x8*)(sB1 + boff[fn]);
#pragma unroll
        for (int fn = 0; fn < 2; ++fn) v[fn] = *(const bf16x8*)(sB2 + boff[fn]);
#pragma unroll
        for (int fm = 0; fm < 4; ++fm)
#pragma unroll
            for (int fn = 0; fn < 2; ++fn) {
                acc1[fm][fn] = __builtin_amdgcn_mfma_f32_16x16x32_bf16(a[fm], u[fn], acc1[fm][fn], 0, 0, 0);
                acc2[fm][fn] = __builtin_amdgcn_mfma_f32_16x16x32_bf16(a[fm], v[fn], acc2[fm][fn], 0, 0, 0);
            }
    };

    STAGE(0, 0);
    __syncthreads();
#pragma unroll 1
    for (int kt = 0; kt < 64; ++kt) {
        if (kt + 1 < 64) STAGE((kt + 1) & 1, kt + 1);
        COMPUTE(kt & 1);
        __syncthreads();
    }

    // epilogue: k-reduce (cols = lane&15 are the 16 k's of one o) via shfl_xor
    const int obase = nt * 8 + wn * 2;
#pragma unroll
    for (int fn = 0; fn < 2; ++fn) {
        const int o = obase + fn;
        const float bb1 = b1[(size_t)o * 16 + lk];
        const float bb2 = b2[o];
#pragma unroll
        for (int fm = 0; fm < 4; ++fm) {
#pragma unroll
            for (int j = 0; j < 4; ++j) {
                float g = fmaxf(acc1[fm][fn][j] + bb1, 0.f);
                float p = g * acc2[fm][fn][j];
                p += __shfl_xor(p, 1);
                p += __shfl_xor(p, 2);
                p += __shfl_xor(p, 4);
                p += __shfl_xor(p, 8);
                if (lk == 0) {
                    const int brow = mt * 128 + wm * 64 + fm * 16 + lg * 4 + j;
                    out[(size_t)brow * DOUT_ + o] = p + bb2;
                }
            }
        }
    }
}

// ---------------- fallback: round-1 kernel (verified passing) ----------------
__global__ __launch_bounds__(512)
void mix2_fused_direct(const float* __restrict__ x, const float* __restrict__ w1,
                       const float* __restrict__ b1, const float* __restrict__ w2,
                       const float* __restrict__ b2, float* __restrict__ out)
{
    __shared__ alignas(16) char lds[2 * 49152];

    const int tid  = threadIdx.x;
    const int lane = tid & 63;
    const int wid  = tid >> 6;
    const int wm   = wid >> 2;
    const int wn   = wid & 3;

    const int nwg = gridDim.x;
    const int bid = (blockIdx.x & 7) * (nwg >> 3) + (blockIdx.x >> 3);
    const int mt  = bid & 15;
    const int nt  = bid >> 4;

    const int lk  = lane & 15;
    const int lg  = lane >> 4;
    const int swz = (lane & 7) << 4;

    const int a_row  = tid >> 3;
    const int a_col8 = tid & 7;
    const int b_ib = ((tid >> 5) & 15) << 2;
    const int b_nb = (tid & 31) << 2;

    const float* pa  = x  + (size_t)(mt * 128 + a_row) * DIN_ + a_col8 * 8;
    const float* pb1 = w1 + (size_t)b_ib * NP_ + (size_t)nt * 128 + b_nb;
    const float* pb2 = w2 + (size_t)b_ib * NP_ + (size_t)nt * 128 + b_nb;

    const int aswz   = (a_col8 * 16) ^ ((a_row & 7) << 4);
    const int aoffw0 = a_row * 128 + aswz;
    const int aoffw1 = (a_row + 64) * 128 + aswz;

    int aoff[4], boff1[2], boff2[2];
#pragma unroll
    for (int fm = 0; fm < 4; ++fm) aoff[fm] = (wm * 64 + fm * 16 + lk) * 128;
#pragma unroll
    for (int fn = 0; fn < 2; ++fn) {
        const int n = wn * 32 + fn * 16 + lk;
        boff1[fn] = 16384 + n * 128;
        boff2[fn] = 32768 + n * 128;
    }
    const int kp0 = (lg * 16) ^ swz;
    const int kp1 = (64 + lg * 16) ^ swz;

    f32x4 acc1[4][2], acc2[4][2];
#pragma unroll
    for (int i = 0; i < 4; ++i)
#pragma unroll
        for (int j = 0; j < 2; ++j) {
            acc1[i][j] = (f32x4){0.f, 0.f, 0.f, 0.f};
            acc2[i][j] = (f32x4){0.f, 0.f, 0.f, 0.f};
        }

    f32x4 rA[4], rB1[4], rB2[4];

    auto LOAD = [&](int kt) {
        const float* a0 = pa + kt * 64;
        rA[0] = *(const f32x4*)(a0);
        rA[1] = *(const f32x4*)(a0 + 4);
        rA[2] = *(const f32x4*)(a0 + (size_t)64 * DIN_);
        rA[3] = *(const f32x4*)(a0 + (size_t)64 * DIN_ + 4);
        const float* q1 = pb1 + (size_t)kt * 64 * NP_;
        const float* q2 = pb2 + (size_t)kt * 64 * NP_;
#pragma unroll
        for (int j = 0; j < 4; ++j) {
            rB1[j] = *(const f32x4*)(q1 + (size_t)j * NP_);
            rB2[j] = *(const f32x4*)(q2 + (size_t)j * NP_);
        }
    };

    auto STORE = [&](char* s) {
        *(bf16x8*)(s + aoffw0) = cvt8(rA[0], rA[1]);
        *(bf16x8*)(s + aoffw1) = cvt8(rA[2], rA[3]);
        char* s1 = s + 16384;
        char* s2 = s + 32768;
#pragma unroll
        for (int c = 0; c < 4; ++c) {
            const int n   = b_nb + c;
            const int off = n * 128 + ((b_ib * 2) ^ ((n & 7) << 4));
            bf16x4 v1, v2;
            v1[0] = (bf16)rB1[0][c]; v1[1] = (bf16)rB1[1][c];
            v1[2] = (bf16)rB1[2][c]; v1[3] = (bf16)rB1[3][c];
            v2[0] = (bf16)rB2[0][c]; v2[1] = (bf16)rB2[1][c];
            v2[2] = (bf16)rB2[2][c]; v2[3] = (bf16)rB2[3][c];
            *(bf16x4*)(s1 + off) = v1;
            *(bf16x4*)(s2 + off) = v2;
        }
    };

    auto COMPUTE = [&](const char* s) {
#pragma unroll
        for (int kb = 0; kb < 2; ++kb) {
            const int kp = kb ? kp1 : kp0;
            bf16x8 a[4], u[2], v[2];
#pragma unroll
            for (int fm = 0; fm < 4; ++fm) a[fm] = *(const bf16x8*)(s + aoff[fm] + kp);
#pragma unroll
            for (int fn = 0; fn < 2; ++fn) u[fn] = *(const bf16x8*)(s + boff1[fn] + kp);
#pragma unroll
            for (int fn = 0; fn < 2; ++fn) v[fn] = *(const bf16x8*)(s + boff2[fn] + kp);
#pragma unroll
            for (int fm = 0; fm < 4; ++fm)
#pragma unroll
                for (int fn = 0; fn < 2; ++fn) {
                    acc1[fm][fn] = __builtin_amdgcn_mfma_f32_16x16x32_bf16(a[fm], u[fn], acc1[fm][fn], 0, 0, 0);
                    acc2[fm][fn] = __builtin_amdgcn_mfma_f32_16x16x32_bf16(a[fm], v[fn], acc2[fm][fn], 0, 0, 0);
                }
        }
    };

    char* buf0 = lds;
    char* buf1 = lds + 49152;

    LOAD(0);
    STORE(buf0);
    __syncthreads();

    for (int kt = 0; kt < 32; ++kt) {
        if (kt + 1 < 32) LOAD(kt + 1);
        COMPUTE((kt & 1) ? buf1 : buf0);
        if (kt + 1 < 32) {
            STORE((kt & 1) ? buf0 : buf1);
            __syncthreads();
        }
    }

    const int obase = nt * 8 + wn * 2;
#pragma unroll
    for (int fn = 0; fn < 2; ++fn) {
        const int o = obase + fn;
        const float bb1 = b1[(size_t)o * 16 + lk];
        const float bb2 = b2[o];
#pragma unroll
        for (int fm = 0; fm < 4; ++fm) {
#pragma unroll
            for (int j = 0; j < 4; ++j) {
                float g = fmaxf(acc1[fm][fn][j] + bb1, 0.f);
                float p = g * acc2[fm][fn][j];
                p += __shfl_xor(p, 1);
                p += __shfl_xor(p, 2);
                p += __shfl_xor(p, 4);
                p += __shfl_xor(p, 8);
                if (lk == 0) {
                    const int brow = mt * 128 + wm * 64 + fm * 16 + lg * 4 + j;
                    out[(size_t)brow * DOUT_ + o] = p + bb2;
                }
            }
        }
    }
}

extern "C" void kernel_launch(void* const* d_in, const int* in_sizes, int n_in,
                              void* d_out, int out_size, void* d_ws, size_t ws_size,
                              hipStream_t stream) {
    (void)in_sizes; (void)n_in; (void)out_size;
    const float* x  = (const float*)d_in[0];
    const float* w1 = (const float*)d_in[1];
    const float* b1 = (const float*)d_in[2];
    const float* w2 = (const float*)d_in[3];
    const float* b2 = (const float*)d_in[4];
    float* out = (float*)d_out;

    const size_t XB   = (size_t)DIN_ * DIN_ * 2;            // 8 MB   (x bf16)
    const size_t WT   = (size_t)NP_ * DIN_ * 2;             // 128 MB (each wt)
    const size_t NEED = XB + 2 * WT;                        // 264 MB

    if (ws_size >= NEED) {
        bf16* xb  = (bf16*)d_ws;
        bf16* w1t = (bf16*)((char*)d_ws + XB);
        bf16* w2t = (bf16*)((char*)d_ws + XB + WT);
        hipLaunchKernelGGL(xcvt,   dim3(2048),       dim3(256), 0, stream, x, xb);
        hipLaunchKernelGGL(wtrans, dim3(512, 32, 2), dim3(256), 0, stream, w1, w2, w1t, w2t);
        hipLaunchKernelGGL(mix2_gemm, dim3(4096),    dim3(512), 0, stream, xb, w1t, w2t, b1, b2, out);
    } else {
        hipLaunchKernelGGL(mix2_fused_direct, dim3(4096), dim3(512), 0, stream, x, w1, b1, w2, b2, out);
    }
}

// Round 3
// 701.438 us; speedup vs baseline: 1.7038x; 1.0815x over previous
//
#include <hip/hip_runtime.h>
#include <hip/hip_bf16.h>

// Mix2Layer: out[b,o] = sum_k relu(sum_i x[b,i]*w1[i,o,k] + b1[o,k]) * (sum_i x[b,i]*w2[i,o,k]) + b2[o]
// B=2048, DIN=2048, DOUT=2048, K=16.  N' = o*16+k (w row-major [DIN][32768]).
//
// Fast path (needs ws >= 264MB):
//   1) xcvt:   x fp32 -> bf16                  (8 MB)
//   2) wtrans: w[i][n'] fp32 -> wt[n'][i] bf16 (128 MB each)
//   3) mix2_gemm8: dual-B bf16 GEMM, 8-phase counted-vmcnt schedule (T3+T4+T5),
//      tile 256(m)x128(n'), BK=64 as 2x32 halves, 128KB LDS dbuf,
//      global_load_lds w/ pre-swizzled source (bank-conflict-free reads).
// Fallback: round-1 in-kernel-transpose kernel (verified passing).

typedef __bf16 bf16;
typedef bf16 bf16x8 __attribute__((ext_vector_type(8)));
typedef bf16 bf16x4 __attribute__((ext_vector_type(4)));
typedef float f32x4 __attribute__((ext_vector_type(4)));

typedef __attribute__((address_space(1))) const void gco_void;
typedef __attribute__((address_space(3))) void lds_void;

#define DIN_   2048
#define DOUT_  2048
#define NP_    32768   // DOUT*K

__device__ __forceinline__ bf16x8 cvt8(f32x4 a, f32x4 b) {
    bf16x8 v;
    v[0] = (bf16)a[0]; v[1] = (bf16)a[1]; v[2] = (bf16)a[2]; v[3] = (bf16)a[3];
    v[4] = (bf16)b[0]; v[5] = (bf16)b[1]; v[6] = (bf16)b[2]; v[7] = (bf16)b[3];
    return v;
}

// ---------------- prep 1: x fp32 -> bf16 ----------------
__global__ __launch_bounds__(256)
void xcvt(const float* __restrict__ x, bf16* __restrict__ xb) {
    const size_t i = ((size_t)blockIdx.x * 256 + threadIdx.x) * 8;
    f32x4 a = *(const f32x4*)(x + i);
    f32x4 b = *(const f32x4*)(x + i + 4);
    *(bf16x8*)(xb + i) = cvt8(a, b);
}

// ---------------- prep 2: w[i][n'] fp32 -> wt[n'][i] bf16 ----------------
__global__ __launch_bounds__(256)
void wtrans(const float* __restrict__ w1, const float* __restrict__ w2,
            bf16* __restrict__ w1t, bf16* __restrict__ w2t) {
    __shared__ float s[64][65];
    const int t  = threadIdx.x;
    const int lr = t >> 4;      // 0..15
    const int lq = t & 15;      // 0..15
    const int n0 = blockIdx.x * 64;
    const int i0 = blockIdx.y * 64;
    const float* src = blockIdx.z ? w2 : w1;
    bf16*        dst = blockIdx.z ? w2t : w1t;
#pragma unroll
    for (int r = 0; r < 4; ++r) {
        const int il = lr + 16 * r;
        f32x4 v = *(const f32x4*)(src + (size_t)(i0 + il) * NP_ + n0 + lq * 4);
        s[il][lq * 4 + 0] = v[0]; s[il][lq * 4 + 1] = v[1];
        s[il][lq * 4 + 2] = v[2]; s[il][lq * 4 + 3] = v[3];
    }
    __syncthreads();
#pragma unroll
    for (int r = 0; r < 4; ++r) {
        const int nl = lr + 16 * r;
        bf16x4 o;
        o[0] = (bf16)s[lq * 4 + 0][nl]; o[1] = (bf16)s[lq * 4 + 1][nl];
        o[2] = (bf16)s[lq * 4 + 2][nl]; o[3] = (bf16)s[lq * 4 + 3][nl];
        *(bf16x4*)(dst + (size_t)(n0 + nl) * DIN_ + i0 + lq * 4) = o;
    }
}

// ---------------- main: 8-phase dual-B GEMM ----------------
// Tile 256(m) x 128(n'), BK=64 (2 halves of 32k). 8 waves (2m x 4n).
// LDS buffer layout (65536B per buffer, 2 buffers):
//   half kb (32768B each): [A 256x32k 16KB][B1 128x32k 8KB][B2 128x32k 8KB]
// rows are 64B (32 k-elems); 16B slots pre-swizzled: phys = slot ^ ((row>>1)&3).
// Staging: 4 gload_lds(16B)/wave/half; vmcnt(4) = one half in flight allowed.
#define MIDSYNC() do { __builtin_amdgcn_s_barrier(); \
    asm volatile("s_waitcnt lgkmcnt(0)" ::: "memory"); \
    __builtin_amdgcn_sched_barrier(0); } while (0)
#define ENDBAR()  do { __builtin_amdgcn_s_barrier(); \
    asm volatile("" ::: "memory"); } while (0)

__global__ __launch_bounds__(512, 2)
void mix2_gemm8(const bf16* __restrict__ xb, const bf16* __restrict__ w1t,
                const bf16* __restrict__ w2t, const float* __restrict__ b1,
                const float* __restrict__ b2, float* __restrict__ out)
{
    __shared__ alignas(16) char lds[131072];

    const int tid  = threadIdx.x;
    const int lane = tid & 63;
    const int wid  = tid >> 6;     // 0..7
    const int wm   = wid >> 2;     // 0..1  (128-row slab)
    const int wn   = wid & 3;      // 0..3  (32-col slab)
    const int lk   = lane & 15;
    const int lg   = lane >> 4;

    const int nwg = gridDim.x;     // 2048
    const int bid = (blockIdx.x & 7) * (nwg >> 3) + (blockIdx.x >> 3);
    const int mt  = bid & 7;       // 8 m-tiles of 256
    const int nt  = bid >> 3;      // 256 n-panels of 128

    // staging mapping: chunk c -> row=c>>2, phys slot=c&3 holds global slot^((row>>1)&3)
    const int srow = tid >> 2;                      // 0..127
    const int sswz = ((tid & 3) ^ ((srow >> 1) & 3)) * 8;
    const bf16* gA  = xb  + (size_t)(mt * 256 + srow) * DIN_ + sswz;   // +128*DIN_ for rows 128..255
    const bf16* gB1 = w1t + (size_t)(nt * 128 + srow) * DIN_ + sswz;
    const bf16* gB2 = w2t + (size_t)(nt * 128 + srow) * DIN_ + sswz;

    // fragment read offsets (bytes within a 32k half)
    const int kswz = (lg ^ ((lk >> 1) & 3)) * 16;
    int aoff[8], boff[2];
#pragma unroll
    for (int fm = 0; fm < 8; ++fm) aoff[fm] = (wm * 128 + fm * 16 + lk) * 64 + kswz;
#pragma unroll
    for (int fn = 0; fn < 2; ++fn) boff[fn] = (wn * 32 + fn * 16 + lk) * 64 + kswz;

    f32x4 acc1[8][2], acc2[8][2];
#pragma unroll
    for (int i = 0; i < 8; ++i)
#pragma unroll
        for (int j = 0; j < 2; ++j) {
            acc1[i][j] = (f32x4){0.f, 0.f, 0.f, 0.f};
            acc2[i][j] = (f32x4){0.f, 0.f, 0.f, 0.f};
        }

    const int ldw = wid * 1024;
    auto STG_A1B1 = [&](char* hb, int koff) {
        __builtin_amdgcn_global_load_lds((gco_void*)(gA  + koff), (lds_void*)(hb + ldw),         16, 0, 0);
        __builtin_amdgcn_global_load_lds((gco_void*)(gB1 + koff), (lds_void*)(hb + 16384 + ldw), 16, 0, 0);
    };
    auto STG_A2B2 = [&](char* hb, int koff) {
        __builtin_amdgcn_global_load_lds((gco_void*)(gA + 128 * DIN_ + koff), (lds_void*)(hb + 8192 + ldw), 16, 0, 0);
        __builtin_amdgcn_global_load_lds((gco_void*)(gB2 + koff), (lds_void*)(hb + 24576 + ldw), 16, 0, 0);
    };
    auto LDB = [&](const char* hb, bf16x8 u[2], bf16x8 v[2]) {
#pragma unroll
        for (int fn = 0; fn < 2; ++fn) {
            u[fn] = *(const bf16x8*)(hb + 16384 + boff[fn]);
            v[fn] = *(const bf16x8*)(hb + 24576 + boff[fn]);
        }
    };

    // prologue: stage both halves of tile 0 into buf0
    STG_A1B1(lds, 0);          STG_A2B2(lds, 0);
    STG_A1B1(lds + 32768, 32); STG_A2B2(lds + 32768, 32);
    asm volatile("s_waitcnt vmcnt(4)" ::: "memory");   // half0 landed (half1 in flight)
    __builtin_amdgcn_s_barrier();
    asm volatile("" ::: "memory");

#pragma unroll 1
    for (int t = 0; t < 32; ++t) {
        char* bufc = lds + (t & 1) * 65536;
        char* bufn = lds + ((t + 1) & 1) * 65536;
        const bool pf = (t + 1) < 32;
        const int koff = (t + 1) * 64;
        bf16x8 a[4], u[2], v[2];

#pragma unroll
        for (int kb = 0; kb < 2; ++kb) {
            const char* hb = bufc + kb * 32768;
            char* hn = bufn + kb * 32768;
            const int kon = koff + kb * 32;

            // ---- phase A (fm 0..3) ----
            LDB(hb, u, v);
#pragma unroll
            for (int j = 0; j < 4; ++j) a[j] = *(const bf16x8*)(hb + aoff[j]);
            if (pf) STG_A1B1(hn, kon);
            MIDSYNC();
            __builtin_amdgcn_s_setprio(1);
#pragma unroll
            for (int j = 0; j < 4; ++j)
#pragma unroll
                for (int fn = 0; fn < 2; ++fn) {
                    acc1[j][fn] = __builtin_amdgcn_mfma_f32_16x16x32_bf16(a[j], u[fn], acc1[j][fn], 0, 0, 0);
                    acc2[j][fn] = __builtin_amdgcn_mfma_f32_16x16x32_bf16(a[j], v[fn], acc2[j][fn], 0, 0, 0);
                }
            __builtin_amdgcn_s_setprio(0);
            ENDBAR();

            // ---- phase B (fm 4..7) ----
#pragma unroll
            for (int j = 0; j < 4; ++j) a[j] = *(const bf16x8*)(hb + aoff[4 + j]);
            if (pf) STG_A2B2(hn, kon);
            MIDSYNC();
            __builtin_amdgcn_s_setprio(1);
#pragma unroll
            for (int j = 0; j < 4; ++j)
#pragma unroll
                for (int fn = 0; fn < 2; ++fn) {
                    acc1[4 + j][fn] = __builtin_amdgcn_mfma_f32_16x16x32_bf16(a[j], u[fn], acc1[4 + j][fn], 0, 0, 0);
                    acc2[4 + j][fn] = __builtin_amdgcn_mfma_f32_16x16x32_bf16(a[j], v[fn], acc2[4 + j][fn], 0, 0, 0);
                }
            __builtin_amdgcn_s_setprio(0);
            // counted wait for the NEXT half's staging (issued one phase-pair ago)
            if (kb == 0) {
                if (pf) asm volatile("s_waitcnt vmcnt(4)" ::: "memory");
                else    asm volatile("s_waitcnt vmcnt(0)" ::: "memory");
            } else if (pf) {
                asm volatile("s_waitcnt vmcnt(4)" ::: "memory");
            }
            ENDBAR();
        }
    }

    // ---- epilogue: k-reduce via shfl_xor, cols lane&15 = 16 k's of one o ----
    const int obase = nt * 8 + wn * 2;
#pragma unroll
    for (int fn = 0; fn < 2; ++fn) {
        const int o = obase + fn;
        const float bb1 = b1[(size_t)o * 16 + lk];
        const float bb2 = b2[o];
#pragma unroll
        for (int fm = 0; fm < 8; ++fm) {
#pragma unroll
            for (int j = 0; j < 4; ++j) {
                float g = fmaxf(acc1[fm][fn][j] + bb1, 0.f);
                float p = g * acc2[fm][fn][j];
                p += __shfl_xor(p, 1);
                p += __shfl_xor(p, 2);
                p += __shfl_xor(p, 4);
                p += __shfl_xor(p, 8);
                if (lk == 0) {
                    const int brow = mt * 256 + wm * 128 + fm * 16 + lg * 4 + j;
                    out[(size_t)brow * DOUT_ + o] = p + bb2;
                }
            }
        }
    }
}

// ---------------- fallback: round-1 kernel (verified passing) ----------------
__global__ __launch_bounds__(512)
void mix2_fused_direct(const float* __restrict__ x, const float* __restrict__ w1,
                       const float* __restrict__ b1, const float* __restrict__ w2,
                       const float* __restrict__ b2, float* __restrict__ out)
{
    __shared__ alignas(16) char lds[2 * 49152];

    const int tid  = threadIdx.x;
    const int lane = tid & 63;
    const int wid  = tid >> 6;
    const int wm   = wid >> 2;
    const int wn   = wid & 3;

    const int nwg = gridDim.x;
    const int bid = (blockIdx.x & 7) * (nwg >> 3) + (blockIdx.x >> 3);
    const int mt  = bid & 15;
    const int nt  = bid >> 4;

    const int lk  = lane & 15;
    const int lg  = lane >> 4;
    const int swz = (lane & 7) << 4;

    const int a_row  = tid >> 3;
    const int a_col8 = tid & 7;
    const int b_ib = ((tid >> 5) & 15) << 2;
    const int b_nb = (tid & 31) << 2;

    const float* pa  = x  + (size_t)(mt * 128 + a_row) * DIN_ + a_col8 * 8;
    const float* pb1 = w1 + (size_t)b_ib * NP_ + (size_t)nt * 128 + b_nb;
    const float* pb2 = w2 + (size_t)b_ib * NP_ + (size_t)nt * 128 + b_nb;

    const int aswz   = (a_col8 * 16) ^ ((a_row & 7) << 4);
    const int aoffw0 = a_row * 128 + aswz;
    const int aoffw1 = (a_row + 64) * 128 + aswz;

    int aoff[4], boff1[2], boff2[2];
#pragma unroll
    for (int fm = 0; fm < 4; ++fm) aoff[fm] = (wm * 64 + fm * 16 + lk) * 128;
#pragma unroll
    for (int fn = 0; fn < 2; ++fn) {
        const int n = wn * 32 + fn * 16 + lk;
        boff1[fn] = 16384 + n * 128;
        boff2[fn] = 32768 + n * 128;
    }
    const int kp0 = (lg * 16) ^ swz;
    const int kp1 = (64 + lg * 16) ^ swz;

    f32x4 acc1[4][2], acc2[4][2];
#pragma unroll
    for (int i = 0; i < 4; ++i)
#pragma unroll
        for (int j = 0; j < 2; ++j) {
            acc1[i][j] = (f32x4){0.f, 0.f, 0.f, 0.f};
            acc2[i][j] = (f32x4){0.f, 0.f, 0.f, 0.f};
        }

    f32x4 rA[4], rB1[4], rB2[4];

    auto LOAD = [&](int kt) {
        const float* a0 = pa + kt * 64;
        rA[0] = *(const f32x4*)(a0);
        rA[1] = *(const f32x4*)(a0 + 4);
        rA[2] = *(const f32x4*)(a0 + (size_t)64 * DIN_);
        rA[3] = *(const f32x4*)(a0 + (size_t)64 * DIN_ + 4);
        const float* q1 = pb1 + (size_t)kt * 64 * NP_;
        const float* q2 = pb2 + (size_t)kt * 64 * NP_;
#pragma unroll
        for (int j = 0; j < 4; ++j) {
            rB1[j] = *(const f32x4*)(q1 + (size_t)j * NP_);
            rB2[j] = *(const f32x4*)(q2 + (size_t)j * NP_);
        }
    };

    auto STORE = [&](char* s) {
        *(bf16x8*)(s + aoffw0) = cvt8(rA[0], rA[1]);
        *(bf16x8*)(s + aoffw1) = cvt8(rA[2], rA[3]);
        char* s1 = s + 16384;
        char* s2 = s + 32768;
#pragma unroll
        for (int c = 0; c < 4; ++c) {
            const int n   = b_nb + c;
            const int off = n * 128 + ((b_ib * 2) ^ ((n & 7) << 4));
            bf16x4 v1, v2;
            v1[0] = (bf16)rB1[0][c]; v1[1] = (bf16)rB1[1][c];
            v1[2] = (bf16)rB1[2][c]; v1[3] = (bf16)rB1[3][c];
            v2[0] = (bf16)rB2[0][c]; v2[1] = (bf16)rB2[1][c];
            v2[2] = (bf16)rB2[2][c]; v2[3] = (bf16)rB2[3][c];
            *(bf16x4*)(s1 + off) = v1;
            *(bf16x4*)(s2 + off) = v2;
        }
    };

    auto COMPUTE = [&](const char* s) {
#pragma unroll
        for (int kb = 0; kb < 2; ++kb) {
            const int kp = kb ? kp1 : kp0;
            bf16x8 a[4], u[2], v[2];
#pragma unroll
            for (int fm = 0; fm < 4; ++fm) a[fm] = *(const bf16x8*)(s + aoff[fm] + kp);
#pragma unroll
            for (int fn = 0; fn < 2; ++fn) u[fn] = *(const bf16x8*)(s + boff1[fn] + kp);
#pragma unroll
            for (int fn = 0; fn < 2; ++fn) v[fn] = *(const bf16x8*)(s + boff2[fn] + kp);
#pragma unroll
            for (int fm = 0; fm < 4; ++fm)
#pragma unroll
                for (int fn = 0; fn < 2; ++fn) {
                    acc1[fm][fn] = __builtin_amdgcn_mfma_f32_16x16x32_bf16(a[fm], u[fn], acc1[fm][fn], 0, 0, 0);
                    acc2[fm][fn] = __builtin_amdgcn_mfma_f32_16x16x32_bf16(a[fm], v[fn], acc2[fm][fn], 0, 0, 0);
                }
        }
    };

    char* buf0 = lds;
    char* buf1 = lds + 49152;

    LOAD(0);
    STORE(buf0);
    __syncthreads();

    for (int kt = 0; kt < 32; ++kt) {
        if (kt + 1 < 32) LOAD(kt + 1);
        COMPUTE((kt & 1) ? buf1 : buf0);
        if (kt + 1 < 32) {
            STORE((kt & 1) ? buf0 : buf1);
            __syncthreads();
        }
    }

    const int obase = nt * 8 + wn * 2;
#pragma unroll
    for (int fn = 0; fn < 2; ++fn) {
        const int o = obase + fn;
        const float bb1 = b1[(size_t)o * 16 + lk];
        const float bb2 = b2[o];
#pragma unroll
        for (int fm = 0; fm < 4; ++fm) {
#pragma unroll
            for (int j = 0; j < 4; ++j) {
                float g = fmaxf(acc1[fm][fn][j] + bb1, 0.f);
                float p = g * acc2[fm][fn][j];
                p += __shfl_xor(p, 1);
                p += __shfl_xor(p, 2);
                p += __shfl_xor(p, 4);
                p += __shfl_xor(p, 8);
                if (lk == 0) {
                    const int brow = mt * 128 + wm * 64 + fm * 16 + lg * 4 + j;
                    out[(size_t)brow * DOUT_ + o] = p + bb2;
                }
            }
        }
    }
}

extern "C" void kernel_launch(void* const* d_in, const int* in_sizes, int n_in,
                              void* d_out, int out_size, void* d_ws, size_t ws_size,
                              hipStream_t stream) {
    (void)in_sizes; (void)n_in; (void)out_size;
    const float* x  = (const float*)d_in[0];
    const float* w1 = (const float*)d_in[1];
    const float* b1 = (const float*)d_in[2];
    const float* w2 = (const float*)d_in[3];
    const float* b2 = (const float*)d_in[4];
    float* out = (float*)d_out;

    const size_t XB   = (size_t)DIN_ * DIN_ * 2;            // 8 MB   (x bf16)
    const size_t WT   = (size_t)NP_ * DIN_ * 2;             // 128 MB (each wt)
    const size_t NEED = XB + 2 * WT;                        // 264 MB

    if (ws_size >= NEED) {
        bf16* xb  = (bf16*)d_ws;
        bf16* w1t = (bf16*)((char*)d_ws + XB);
        bf16* w2t = (bf16*)((char*)d_ws + XB + WT);
        hipLaunchKernelGGL(xcvt,   dim3(2048),       dim3(256), 0, stream, x, xb);
        hipLaunchKernelGGL(wtrans, dim3(512, 32, 2), dim3(256), 0, stream, w1, w2, w1t, w2t);
        hipLaunchKernelGGL(mix2_gemm8, dim3(2048),   dim3(512), 0, stream, xb, w1t, w2t, b1, b2, out);
    } else {
        hipLaunchKernelGGL(mix2_fused_direct, dim3(4096), dim3(512), 0, stream, x, w1, b1, w2, b2, out);
    }
}

// Round 4
// 683.126 us; speedup vs baseline: 1.7494x; 1.0268x over previous
//
#include <hip/hip_runtime.h>
#include <hip/hip_bf16.h>

// Mix2Layer: out[b,o] = sum_k relu(sum_i x[b,i]*w1[i,o,k] + b1[o,k]) * (sum_i x[b,i]*w2[i,o,k]) + b2[o]
// B=2048, DIN=2048, DOUT=2048, K=16.  N' = o*16+k (w row-major [DIN][32768]).
//
// Fast path (needs ws >= 264MB):
//   1) xcvt:   x fp32 -> bf16                  (8 MB)
//   2) wtrans: w[i][n'] fp32 -> wt[n'][i] bf16 (128 MB each)
//   3) mix2_gemmr: dual-B bf16 GEMM, ring-of-4 half-tile schedule:
//      one barrier + counted vmcnt(8) per half, staging 3 halves deep,
//      compiler-counted lgkm between ds_reads and MFMA (no lgkmcnt(0)).
// Fallback: round-1 in-kernel-transpose kernel (verified passing).

typedef __bf16 bf16;
typedef bf16 bf16x8 __attribute__((ext_vector_type(8)));
typedef bf16 bf16x4 __attribute__((ext_vector_type(4)));
typedef float f32x4 __attribute__((ext_vector_type(4)));

typedef __attribute__((address_space(1))) const void gco_void;
typedef __attribute__((address_space(3))) void lds_void;

#define DIN_   2048
#define DOUT_  2048
#define NP_    32768   // DOUT*K

__device__ __forceinline__ bf16x8 cvt8(f32x4 a, f32x4 b) {
    bf16x8 v;
    v[0] = (bf16)a[0]; v[1] = (bf16)a[1]; v[2] = (bf16)a[2]; v[3] = (bf16)a[3];
    v[4] = (bf16)b[0]; v[5] = (bf16)b[1]; v[6] = (bf16)b[2]; v[7] = (bf16)b[3];
    return v;
}

// ---------------- prep 1: x fp32 -> bf16 ----------------
__global__ __launch_bounds__(256)
void xcvt(const float* __restrict__ x, bf16* __restrict__ xb) {
    const size_t i = ((size_t)blockIdx.x * 256 + threadIdx.x) * 8;
    f32x4 a = *(const f32x4*)(x + i);
    f32x4 b = *(const f32x4*)(x + i + 4);
    *(bf16x8*)(xb + i) = cvt8(a, b);
}

// ---------------- prep 2: w[i][n'] fp32 -> wt[n'][i] bf16 ----------------
__global__ __launch_bounds__(256)
void wtrans(const float* __restrict__ w1, const float* __restrict__ w2,
            bf16* __restrict__ w1t, bf16* __restrict__ w2t) {
    __shared__ float s[64][65];
    const int t  = threadIdx.x;
    const int lr = t >> 4;      // 0..15
    const int lq = t & 15;      // 0..15
    const int n0 = blockIdx.x * 64;
    const int i0 = blockIdx.y * 64;
    const float* src = blockIdx.z ? w2 : w1;
    bf16*        dst = blockIdx.z ? w2t : w1t;
#pragma unroll
    for (int r = 0; r < 4; ++r) {
        const int il = lr + 16 * r;
        f32x4 v = *(const f32x4*)(src + (size_t)(i0 + il) * NP_ + n0 + lq * 4);
        s[il][lq * 4 + 0] = v[0]; s[il][lq * 4 + 1] = v[1];
        s[il][lq * 4 + 2] = v[2]; s[il][lq * 4 + 3] = v[3];
    }
    __syncthreads();
#pragma unroll
    for (int r = 0; r < 4; ++r) {
        const int nl = lr + 16 * r;
        bf16x4 o;
        o[0] = (bf16)s[lq * 4 + 0][nl]; o[1] = (bf16)s[lq * 4 + 1][nl];
        o[2] = (bf16)s[lq * 4 + 2][nl]; o[3] = (bf16)s[lq * 4 + 3][nl];
        *(bf16x4*)(dst + (size_t)(n0 + nl) * DIN_ + i0 + lq * 4) = o;
    }
}

// ---------------- main: ring-of-4 dual-B GEMM ----------------
// Tile 256(m) x 128(n'); 64 K-halves of 32 k each; ring of 4 LDS regions (32KB):
//   region r = h&3: [A 256x32k 16KB][B1 128x32k 8KB][B2 128x32k 8KB]
// rows 64B; 16B slots pre-swizzled: phys = slot ^ ((row>>1)&3).
// Per phase h: vmcnt(8) ensures S(h) landed (S(h+1),S(h+2) stay in flight);
// barrier; issue S(h+3) (overwrites region read & consumed in phase h-1);
// 12 ds_reads + 32 MFMA, compiler-counted lgkm (no serialization).
#define SYNC8() do { asm volatile("s_waitcnt vmcnt(8)" ::: "memory"); \
    __builtin_amdgcn_s_barrier(); __builtin_amdgcn_sched_barrier(0); } while (0)
#define SYNC4() do { asm volatile("s_waitcnt vmcnt(4)" ::: "memory"); \
    __builtin_amdgcn_s_barrier(); __builtin_amdgcn_sched_barrier(0); } while (0)
#define SYNC0() do { asm volatile("s_waitcnt vmcnt(0)" ::: "memory"); \
    __builtin_amdgcn_s_barrier(); __builtin_amdgcn_sched_barrier(0); } while (0)

__global__ __launch_bounds__(512, 2)
void mix2_gemmr(const bf16* __restrict__ xb, const bf16* __restrict__ w1t,
                const bf16* __restrict__ w2t, const float* __restrict__ b1,
                const float* __restrict__ b2, float* __restrict__ out)
{
    __shared__ alignas(16) char lds[131072];

    const int tid  = threadIdx.x;
    const int lane = tid & 63;
    const int wid  = tid >> 6;     // 0..7
    const int wm   = wid >> 2;     // 0..1  (128-row slab)
    const int wn   = wid & 3;      // 0..3  (32-col slab)
    const int lk   = lane & 15;
    const int lg   = lane >> 4;

    const int nwg = gridDim.x;     // 2048
    const int bid = (blockIdx.x & 7) * (nwg >> 3) + (blockIdx.x >> 3);
    const int mt  = bid & 7;       // 8 m-tiles of 256
    const int nt  = bid >> 3;      // 256 n-panels of 128

    // staging mapping: chunk c -> row=c>>2, phys slot=c&3 holds global slot^((row>>1)&3)
    const int srow = tid >> 2;                      // 0..127
    const int sswz = ((tid & 3) ^ ((srow >> 1) & 3)) * 8;
    const bf16* gA  = xb  + (size_t)(mt * 256 + srow) * DIN_ + sswz;   // +128*DIN_ for rows 128..255
    const bf16* gB1 = w1t + (size_t)(nt * 128 + srow) * DIN_ + sswz;
    const bf16* gB2 = w2t + (size_t)(nt * 128 + srow) * DIN_ + sswz;

    // fragment read offsets (bytes within a region)
    const int kswz = (lg ^ ((lk >> 1) & 3)) * 16;
    int aoff[8], boff[2];
#pragma unroll
    for (int fm = 0; fm < 8; ++fm) aoff[fm] = (wm * 128 + fm * 16 + lk) * 64 + kswz;
#pragma unroll
    for (int fn = 0; fn < 2; ++fn) boff[fn] = (wn * 32 + fn * 16 + lk) * 64 + kswz;

    f32x4 acc1[8][2], acc2[8][2];
#pragma unroll
    for (int i = 0; i < 8; ++i)
#pragma unroll
        for (int j = 0; j < 2; ++j) {
            acc1[i][j] = (f32x4){0.f, 0.f, 0.f, 0.f};
            acc2[i][j] = (f32x4){0.f, 0.f, 0.f, 0.f};
        }

    const int ldw = wid * 1024;
    auto STG = [&](int h) {        // 4 gload_lds into region h&3
        char* r = lds + (h & 3) * 32768;
        const int koff = h * 32;
        __builtin_amdgcn_global_load_lds((gco_void*)(gA  + koff),             (lds_void*)(r +         ldw), 16, 0, 0);
        __builtin_amdgcn_global_load_lds((gco_void*)(gA + 128 * DIN_ + koff), (lds_void*)(r +  8192 + ldw), 16, 0, 0);
        __builtin_amdgcn_global_load_lds((gco_void*)(gB1 + koff),             (lds_void*)(r + 16384 + ldw), 16, 0, 0);
        __builtin_amdgcn_global_load_lds((gco_void*)(gB2 + koff),             (lds_void*)(r + 24576 + ldw), 16, 0, 0);
    };

    auto PHASE = [&](int h) {      // 12 ds_read_b128 + 32 MFMA, compiler-scheduled
        const char* r = lds + (h & 3) * 32768;
        bf16x8 a[8], u[2], v[2];
#pragma unroll
        for (int fn = 0; fn < 2; ++fn) {
            u[fn] = *(const bf16x8*)(r + 16384 + boff[fn]);
            v[fn] = *(const bf16x8*)(r + 24576 + boff[fn]);
        }
#pragma unroll
        for (int fm = 0; fm < 8; ++fm) a[fm] = *(const bf16x8*)(r + aoff[fm]);
        __builtin_amdgcn_s_setprio(1);
#pragma unroll
        for (int fm = 0; fm < 8; ++fm)
#pragma unroll
            for (int fn = 0; fn < 2; ++fn) {
                acc1[fm][fn] = __builtin_amdgcn_mfma_f32_16x16x32_bf16(a[fm], u[fn], acc1[fm][fn], 0, 0, 0);
                acc2[fm][fn] = __builtin_amdgcn_mfma_f32_16x16x32_bf16(a[fm], v[fn], acc2[fm][fn], 0, 0, 0);
            }
        __builtin_amdgcn_s_setprio(0);
    };

    // prologue: stage halves 0,1,2
    STG(0); STG(1); STG(2);

    // phases 0..59 (region = q static under unroll)
#pragma unroll 1
    for (int t = 0; t < 15; ++t) {
        const int h0 = t * 4;
#pragma unroll
        for (int q = 0; q < 4; ++q) {
            SYNC8();
            STG(h0 + q + 3);
            PHASE(h0 + q);
        }
    }
    // tail: h = 60..63
    SYNC8(); STG(63); PHASE(60);
    SYNC8();          PHASE(61);
    SYNC4();          PHASE(62);
    SYNC0();          PHASE(63);

    // ---- epilogue: k-reduce via shfl_xor, cols lane&15 = 16 k's of one o ----
    const int obase = nt * 8 + wn * 2;
#pragma unroll
    for (int fn = 0; fn < 2; ++fn) {
        const int o = obase + fn;
        const float bb1 = b1[(size_t)o * 16 + lk];
        const float bb2 = b2[o];
#pragma unroll
        for (int fm = 0; fm < 8; ++fm) {
#pragma unroll
            for (int j = 0; j < 4; ++j) {
                float g = fmaxf(acc1[fm][fn][j] + bb1, 0.f);
                float p = g * acc2[fm][fn][j];
                p += __shfl_xor(p, 1);
                p += __shfl_xor(p, 2);
                p += __shfl_xor(p, 4);
                p += __shfl_xor(p, 8);
                if (lk == 0) {
                    const int brow = mt * 256 + wm * 128 + fm * 16 + lg * 4 + j;
                    out[(size_t)brow * DOUT_ + o] = p + bb2;
                }
            }
        }
    }
}

// ---------------- fallback: round-1 kernel (verified passing) ----------------
__global__ __launch_bounds__(512)
void mix2_fused_direct(const float* __restrict__ x, const float* __restrict__ w1,
                       const float* __restrict__ b1, const float* __restrict__ w2,
                       const float* __restrict__ b2, float* __restrict__ out)
{
    __shared__ alignas(16) char lds[2 * 49152];

    const int tid  = threadIdx.x;
    const int lane = tid & 63;
    const int wid  = tid >> 6;
    const int wm   = wid >> 2;
    const int wn   = wid & 3;

    const int nwg = gridDim.x;
    const int bid = (blockIdx.x & 7) * (nwg >> 3) + (blockIdx.x >> 3);
    const int mt  = bid & 15;
    const int nt  = bid >> 4;

    const int lk  = lane & 15;
    const int lg  = lane >> 4;
    const int swz = (lane & 7) << 4;

    const int a_row  = tid >> 3;
    const int a_col8 = tid & 7;
    const int b_ib = ((tid >> 5) & 15) << 2;
    const int b_nb = (tid & 31) << 2;

    const float* pa  = x  + (size_t)(mt * 128 + a_row) * DIN_ + a_col8 * 8;
    const float* pb1 = w1 + (size_t)b_ib * NP_ + (size_t)nt * 128 + b_nb;
    const float* pb2 = w2 + (size_t)b_ib * NP_ + (size_t)nt * 128 + b_nb;

    const int aswz   = (a_col8 * 16) ^ ((a_row & 7) << 4);
    const int aoffw0 = a_row * 128 + aswz;
    const int aoffw1 = (a_row + 64) * 128 + aswz;

    int aoff[4], boff1[2], boff2[2];
#pragma unroll
    for (int fm = 0; fm < 4; ++fm) aoff[fm] = (wm * 64 + fm * 16 + lk) * 128;
#pragma unroll
    for (int fn = 0; fn < 2; ++fn) {
        const int n = wn * 32 + fn * 16 + lk;
        boff1[fn] = 16384 + n * 128;
        boff2[fn] = 32768 + n * 128;
    }
    const int kp0 = (lg * 16) ^ swz;
    const int kp1 = (64 + lg * 16) ^ swz;

    f32x4 acc1[4][2], acc2[4][2];
#pragma unroll
    for (int i = 0; i < 4; ++i)
#pragma unroll
        for (int j = 0; j < 2; ++j) {
            acc1[i][j] = (f32x4){0.f, 0.f, 0.f, 0.f};
            acc2[i][j] = (f32x4){0.f, 0.f, 0.f, 0.f};
        }

    f32x4 rA[4], rB1[4], rB2[4];

    auto LOAD = [&](int kt) {
        const float* a0 = pa + kt * 64;
        rA[0] = *(const f32x4*)(a0);
        rA[1] = *(const f32x4*)(a0 + 4);
        rA[2] = *(const f32x4*)(a0 + (size_t)64 * DIN_);
        rA[3] = *(const f32x4*)(a0 + (size_t)64 * DIN_ + 4);
        const float* q1 = pb1 + (size_t)kt * 64 * NP_;
        const float* q2 = pb2 + (size_t)kt * 64 * NP_;
#pragma unroll
        for (int j = 0; j < 4; ++j) {
            rB1[j] = *(const f32x4*)(q1 + (size_t)j * NP_);
            rB2[j] = *(const f32x4*)(q2 + (size_t)j * NP_);
        }
    };

    auto STORE = [&](char* s) {
        *(bf16x8*)(s + aoffw0) = cvt8(rA[0], rA[1]);
        *(bf16x8*)(s + aoffw1) = cvt8(rA[2], rA[3]);
        char* s1 = s + 16384;
        char* s2 = s + 32768;
#pragma unroll
        for (int c = 0; c < 4; ++c) {
            const int n   = b_nb + c;
            const int off = n * 128 + ((b_ib * 2) ^ ((n & 7) << 4));
            bf16x4 v1, v2;
            v1[0] = (bf16)rB1[0][c]; v1[1] = (bf16)rB1[1][c];
            v1[2] = (bf16)rB1[2][c]; v1[3] = (bf16)rB1[3][c];
            v2[0] = (bf16)rB2[0][c]; v2[1] = (bf16)rB2[1][c];
            v2[2] = (bf16)rB2[2][c]; v2[3] = (bf16)rB2[3][c];
            *(bf16x4*)(s1 + off) = v1;
            *(bf16x4*)(s2 + off) = v2;
        }
    };

    auto COMPUTE = [&](const char* s) {
#pragma unroll
        for (int kb = 0; kb < 2; ++kb) {
            const int kp = kb ? kp1 : kp0;
            bf16x8 a[4], u[2], v[2];
#pragma unroll
            for (int fm = 0; fm < 4; ++fm) a[fm] = *(const bf16x8*)(s + aoff[fm] + kp);
#pragma unroll
            for (int fn = 0; fn < 2; ++fn) u[fn] = *(const bf16x8*)(s + boff1[fn] + kp);
#pragma unroll
            for (int fn = 0; fn < 2; ++fn) v[fn] = *(const bf16x8*)(s + boff2[fn] + kp);
#pragma unroll
            for (int fm = 0; fm < 4; ++fm)
#pragma unroll
                for (int fn = 0; fn < 2; ++fn) {
                    acc1[fm][fn] = __builtin_amdgcn_mfma_f32_16x16x32_bf16(a[fm], u[fn], acc1[fm][fn], 0, 0, 0);
                    acc2[fm][fn] = __builtin_amdgcn_mfma_f32_16x16x32_bf16(a[fm], v[fn], acc2[fm][fn], 0, 0, 0);
                }
        }
    };

    char* buf0 = lds;
    char* buf1 = lds + 49152;

    LOAD(0);
    STORE(buf0);
    __syncthreads();

    for (int kt = 0; kt < 32; ++kt) {
        if (kt + 1 < 32) LOAD(kt + 1);
        COMPUTE((kt & 1) ? buf1 : buf0);
        if (kt + 1 < 32) {
            STORE((kt & 1) ? buf0 : buf1);
            __syncthreads();
        }
    }

    const int obase = nt * 8 + wn * 2;
#pragma unroll
    for (int fn = 0; fn < 2; ++fn) {
        const int o = obase + fn;
        const float bb1 = b1[(size_t)o * 16 + lk];
        const float bb2 = b2[o];
#pragma unroll
        for (int fm = 0; fm < 4; ++fm) {
#pragma unroll
            for (int j = 0; j < 4; ++j) {
                float g = fmaxf(acc1[fm][fn][j] + bb1, 0.f);
                float p = g * acc2[fm][fn][j];
                p += __shfl_xor(p, 1);
                p += __shfl_xor(p, 2);
                p += __shfl_xor(p, 4);
                p += __shfl_xor(p, 8);
                if (lk == 0) {
                    const int brow = mt * 128 + wm * 64 + fm * 16 + lg * 4 + j;
                    out[(size_t)brow * DOUT_ + o] = p + bb2;
                }
            }
        }
    }
}

extern "C" void kernel_launch(void* const* d_in, const int* in_sizes, int n_in,
                              void* d_out, int out_size, void* d_ws, size_t ws_size,
                              hipStream_t stream) {
    (void)in_sizes; (void)n_in; (void)out_size;
    const float* x  = (const float*)d_in[0];
    const float* w1 = (const float*)d_in[1];
    const float* b1 = (const float*)d_in[2];
    const float* w2 = (const float*)d_in[3];
    const float* b2 = (const float*)d_in[4];
    float* out = (float*)d_out;

    const size_t XB   = (size_t)DIN_ * DIN_ * 2;            // 8 MB   (x bf16)
    const size_t WT   = (size_t)NP_ * DIN_ * 2;             // 128 MB (each wt)
    const size_t NEED = XB + 2 * WT;                        // 264 MB

    if (ws_size >= NEED) {
        bf16* xb  = (bf16*)d_ws;
        bf16* w1t = (bf16*)((char*)d_ws + XB);
        bf16* w2t = (bf16*)((char*)d_ws + XB + WT);
        hipLaunchKernelGGL(xcvt,   dim3(2048),       dim3(256), 0, stream, x, xb);
        hipLaunchKernelGGL(wtrans, dim3(512, 32, 2), dim3(256), 0, stream, w1, w2, w1t, w2t);
        hipLaunchKernelGGL(mix2_gemmr, dim3(2048),   dim3(512), 0, stream, xb, w1t, w2t, b1, b2, out);
    } else {
        hipLaunchKernelGGL(mix2_fused_direct, dim3(4096), dim3(512), 0, stream, x, w1, b1, w2, b2, out);
    }
}